// Round 10
// baseline (675.586 us; speedup 1.0000x reference)
//
#include <hip/hip_runtime.h>
#include <hip/hip_bf16.h>
#include <hip/hip_cooperative_groups.h>

// GCN on MI355X — SINGLE cooperative kernel, 7 phases split by grid.sync():
//   0: bcursor init + W1/W2 -> bf16 W^T prep
//   1: bin_edges (fixed-cap 256-node buckets, LDS-staged scatter)
//   2: build_rows (per-bucket degree hist -> rowstart/rowend/dinv, colidx)
//   3: gemm1 (MFMA): h1' = dinv ⊙ (x@W1)   -> bufA (bf16)
//   4: agg_mid:  a1 = relu(di*(self+Σh1') + b1) -> bufB (bf16)
//   5: gemm2 (MFMA): h2' = dinv ⊙ (a1@W2)  -> bufA (bf16)
//   6: agg_out:  a2 = relu(di*(self+Σh2') + b2); out = a2@Wc + bc
// Rationale (R9): per-kernel sum ≈175µs vs 285µs measured -> ~100µs of
// inter-dispatch overhead across 8 launches. One cooperative launch
// removes the gaps. Phase bodies identical to R9's verified kernels,
// grid-strided over 512 blocks (2/CU: co-residency guaranteed; LDS
// union 17.4KB, VGPR capped by __launch_bounds__(256,2)).
// Aggregates remain at their random-256B miss-service wall (~2.7TB/s).
// h bf16; accumulation fp32. Requires n <= 65536.

namespace cg = cooperative_groups;

typedef unsigned int uint;
typedef unsigned short ushort;
typedef __attribute__((ext_vector_type(8))) short bf16x8;
typedef __attribute__((ext_vector_type(4))) float f32x4;

#define NPB 256
#define CAP 12288   // edges per bucket region; mean 8192, sd ~90
#define GRID 512    // 2 blocks/CU — all co-resident (cooperative requirement)

static __device__ __forceinline__ ushort f2bf(float f) {
    unsigned u = __float_as_uint(f);
    u += 0x7fffu + ((u >> 16) & 1u);   // round-to-nearest-even
    return (ushort)(u >> 16);
}
static __device__ __forceinline__ uint pack2(float a, float b) {
    return (uint)f2bf(a) | ((uint)f2bf(b) << 16);
}
static __device__ __forceinline__ float lo2f(uint u) { return __uint_as_float(u << 16); }
static __device__ __forceinline__ float hi2f(uint u) { return __uint_as_float(u & 0xffff0000u); }

#define UNPACK8(dst, u)                                        \
    dst[0] = lo2f(u.x); dst[1] = hi2f(u.x);                    \
    dst[2] = lo2f(u.y); dst[3] = hi2f(u.y);                    \
    dst[4] = lo2f(u.z); dst[5] = hi2f(u.z);                    \
    dst[6] = lo2f(u.w); dst[7] = hi2f(u.w);

struct Params {
    const float* x;
    const int* src;
    const int* dst;
    const float* W1;
    const float* b1;
    const float* W2;
    const float* b2;
    const float* Wc;
    const float* bc;
    float* out;
    int* bcursor;
    int* rowstart;
    int* rowend;
    float* dinv;
    ushort* Wt1;
    ushort* Wt2;
    uint* pay;
    int* colidx;
    uint* bufA;
    uint* bufB;
    int n, E, nbuckets, ntile64, ntile16;
};

union __align__(16) SharedU {
    struct { int h[256]; int base[256]; } bin;          // 2 KB
    struct { int hist[256]; int sc[256]; int cur[256]; } br;  // 3 KB
    ushort sOut[4][16][136];                            // 17.4 KB (max)
    float sA[16][129];                                  // 8.3 KB
};

// ---- aggregate gather: one node per 16-lane quarter, 8-edge unrolled ----
static __device__ __forceinline__ void gather_q(const uint4* __restrict__ H4,
                                                int s, int e, int nn, int sub,
                                                const int* __restrict__ colidx,
                                                float acc[8]) {
    uint4 su = H4[(size_t)nn * 16 + sub];
    float t[8];
    UNPACK8(t, su);
#pragma unroll
    for (int j = 0; j < 8; ++j) acc[j] = t[j];   // self term (pre-scaled h')

    int p = s;
    for (; p + 8 <= e; p += 8) {
        int c[8];
#pragma unroll
        for (int i = 0; i < 8; ++i) c[i] = colidx[p + i];
        uint4 u[8];
#pragma unroll
        for (int i = 0; i < 8; ++i) u[i] = H4[(size_t)c[i] * 16 + sub];
#pragma unroll
        for (int i = 0; i < 8; ++i) {
            float a[8];
            UNPACK8(a, u[i]);
#pragma unroll
            for (int j = 0; j < 8; ++j) acc[j] += a[j];
        }
    }
    if (p < e) {
        int c[8];
#pragma unroll
        for (int i = 0; i < 8; ++i) c[i] = (p + i < e) ? colidx[p + i] : nn;
        uint4 u[8];
#pragma unroll
        for (int i = 0; i < 8; ++i) u[i] = H4[(size_t)c[i] * 16 + sub];
#pragma unroll
        for (int i = 0; i < 8; ++i) {
            float a[8];
            UNPACK8(a, u[i]);
#pragma unroll
            for (int j = 0; j < 8; ++j) acc[j] += a[j];
        }
        float pad = (float)(p + 8 - e);   // dummies added self row 'pad' times
#pragma unroll
        for (int j = 0; j < 8; ++j) acc[j] -= pad * t[j];
    }
}

// ---- MFMA GEMM phase: Y = dinv ⊙ (X @ W), grid-strided 64-row tiles ----
template <bool A_BF16>
static __device__ __forceinline__ void gemm_phase(const Params& P, SharedU& sm,
                                                  const void* Xv,
                                                  const ushort* Wt, uint* Yb) {
    const int wave = threadIdx.x >> 6;
    const int lane = threadIdx.x & 63;
    const int quad = lane >> 4, l16 = lane & 15;

    for (int t = blockIdx.x; t < P.ntile64; t += GRID) {
        const int m0 = t * 64 + wave * 16;
        f32x4 acc[8];
#pragma unroll
        for (int i = 0; i < 8; ++i) acc[i] = (f32x4){0.f, 0.f, 0.f, 0.f};

        int arow = m0 + l16;
        arow = arow < P.n ? arow : P.n - 1;

#pragma unroll
        for (int ks = 0; ks < 4; ++ks) {
            bf16x8 a;
            if (A_BF16) {
                const ushort* X = (const ushort*)Xv;
                a = *(const bf16x8*)&X[(size_t)arow * 128 + ks * 32 + quad * 8];
            } else {
                const float* X = (const float*)Xv;
                const float* px = &X[(size_t)arow * 128 + ks * 32 + quad * 8];
                float4 x0 = *(const float4*)px;
                float4 x1 = *(const float4*)(px + 4);
                ushort av[8] = {f2bf(x0.x), f2bf(x0.y), f2bf(x0.z), f2bf(x0.w),
                                f2bf(x1.x), f2bf(x1.y), f2bf(x1.z), f2bf(x1.w)};
                a = *(const bf16x8*)av;
            }
#pragma unroll
            for (int nt = 0; nt < 8; ++nt) {
                bf16x8 b = *(const bf16x8*)&Wt[(size_t)(nt * 16 + l16) * 128 + ks * 32 + quad * 8];
                acc[nt] = __builtin_amdgcn_mfma_f32_16x16x32_bf16(a, b, acc[nt], 0, 0, 0);
            }
        }

        float dv[4];
#pragma unroll
        for (int r = 0; r < 4; ++r) {
            int rr = m0 + quad * 4 + r;
            dv[r] = P.dinv[rr < P.n ? rr : P.n - 1];
        }
        __syncthreads();  // previous iteration's sOut readers done
#pragma unroll
        for (int nt = 0; nt < 8; ++nt)
#pragma unroll
            for (int r = 0; r < 4; ++r)
                sm.sOut[wave][quad * 4 + r][nt * 16 + l16] = f2bf(acc[nt][r] * dv[r]);
        __syncthreads();

#pragma unroll
        for (int i = 0; i < 4; ++i) {
            int linear = i * 64 + lane;
            int row = linear >> 4, chunk = linear & 15;
            int rr = m0 + row;
            if (rr < P.n) {
                uint4 v = *(const uint4*)&sm.sOut[wave][row][chunk * 8];
                *(uint4*)&Yb[(size_t)rr * 64 + chunk * 4] = v;
            }
        }
    }
}

// ---------------- the mega-kernel ----------------
__global__ __launch_bounds__(256, 2) void gcn_all(Params P) {
    cg::grid_group gridg = cg::this_grid();
    __shared__ SharedU sm;
    const int tid = threadIdx.x;
    const int bid = blockIdx.x;
    const int gid = bid * 256 + tid;

    // ---- phase 0: bcursor init + W^T bf16 prep ----
    if (gid < P.nbuckets) P.bcursor[gid] = gid * CAP;
    for (int idx = gid; idx < 128 * 128; idx += GRID * 256) {
        int k = idx >> 7, nn = idx & 127;
        P.Wt1[nn * 128 + k] = f2bf(P.W1[idx]);
        P.Wt2[nn * 128 + k] = f2bf(P.W2[idx]);
    }
    gridg.sync();

    // ---- phase 1: bin_edges ----
    {
        sm.bin.h[tid] = 0;
        __syncthreads();
        int chunk = (P.E + GRID - 1) / GRID;
        int i0 = bid * chunk;
        int i1 = min(P.E, i0 + chunk);
        for (int i = i0 + tid; i < i1; i += 256) atomicAdd(&sm.bin.h[P.dst[i] >> 8], 1);
        __syncthreads();
        if (tid < P.nbuckets)
            sm.bin.base[tid] = sm.bin.h[tid] ? atomicAdd(&P.bcursor[tid], sm.bin.h[tid]) : 0;
        __syncthreads();
        sm.bin.h[tid] = 0;
        __syncthreads();
        for (int i = i0 + tid; i < i1; i += 256) {
            int d = P.dst[i];
            int b = d >> 8;
            int pos = sm.bin.base[b] + atomicAdd(&sm.bin.h[b], 1);
            P.pay[pos] = (uint)P.src[i] | ((uint)(d & 255) << 24);
        }
    }
    gridg.sync();

    // ---- phase 2: build_rows (one bucket per active block) ----
    for (int b = bid; b < P.nbuckets; b += GRID) {
        int node0 = b * NPB;
        int s = b * CAP, e = P.bcursor[b];
        sm.br.hist[tid] = 0;
        __syncthreads();
        for (int i = s + tid; i < e; i += 256) atomicAdd(&sm.br.hist[P.pay[i] >> 24], 1);
        __syncthreads();
        int v = sm.br.hist[tid];
        sm.br.sc[tid] = v;
        __syncthreads();
        for (int d = 1; d < 256; d <<= 1) {
            int xx = (tid >= d) ? sm.br.sc[tid - d] : 0;
            __syncthreads();
            sm.br.sc[tid] += xx;
            __syncthreads();
        }
        int excl = sm.br.sc[tid] - v;
        sm.br.cur[tid] = s + excl;
        int node = node0 + tid;
        if (node < P.n) {
            P.rowstart[node] = s + excl;
            P.rowend[node] = s + excl + v;
            P.dinv[node] = rsqrtf((float)(v + 1));  // +1 self-loop
        }
        __syncthreads();
        for (int i = s + tid; i < e; i += 256) {
            uint pp = P.pay[i];
            int pos = atomicAdd(&sm.br.cur[pp >> 24], 1);
            P.colidx[pos] = (int)(pp & 0xffffffu);
        }
        __syncthreads();
    }
    gridg.sync();

    // ---- phase 3: gemm1 (fp32 x) ----
    gemm_phase<false>(P, sm, P.x, P.Wt1, P.bufA);
    gridg.sync();

    // ---- phase 4: agg_mid -> bufB ----
    {
        const uint4* H4 = (const uint4*)P.bufA;
        uint4* Ob = (uint4*)P.bufB;
        int sub = tid & 15;
        int nl = tid >> 4;
        for (int blk = bid; blk < P.ntile16; blk += GRID) {
            int node = blk * 16 + nl;
            int nn = node < P.n ? node : P.n - 1;
            int s = P.rowstart[nn], e = P.rowend[nn];
            float di = P.dinv[nn];
            float acc[8];
            gather_q(H4, s, e, nn, sub, P.colidx, acc);
            if (node < P.n) {
                float4 b0 = ((const float4*)P.b1)[sub * 2];
                float4 b1v = ((const float4*)P.b1)[sub * 2 + 1];
                uint4 ov;
                ov.x = pack2(fmaxf(fmaf(acc[0], di, b0.x), 0.f),
                             fmaxf(fmaf(acc[1], di, b0.y), 0.f));
                ov.y = pack2(fmaxf(fmaf(acc[2], di, b0.z), 0.f),
                             fmaxf(fmaf(acc[3], di, b0.w), 0.f));
                ov.z = pack2(fmaxf(fmaf(acc[4], di, b1v.x), 0.f),
                             fmaxf(fmaf(acc[5], di, b1v.y), 0.f));
                ov.w = pack2(fmaxf(fmaf(acc[6], di, b1v.z), 0.f),
                             fmaxf(fmaf(acc[7], di, b1v.w), 0.f));
                Ob[(size_t)node * 16 + sub] = ov;
            }
        }
    }
    gridg.sync();

    // ---- phase 5: gemm2 (bf16 a1) ----
    gemm_phase<true>(P, sm, P.bufB, P.Wt2, P.bufA);
    gridg.sync();

    // ---- phase 6: agg_out + classifier ----
    {
        const uint4* H4 = (const uint4*)P.bufA;
        int sub = tid & 15;
        int nl = tid >> 4;
        for (int blk = bid; blk < P.ntile16; blk += GRID) {
            int node = blk * 16 + nl;
            int nn = node < P.n ? node : P.n - 1;
            int s = P.rowstart[nn], e = P.rowend[nn];
            float di = P.dinv[nn];
            float acc[8];
            gather_q(H4, s, e, nn, sub, P.colidx, acc);

            float4 b0 = ((const float4*)P.b2)[sub * 2];
            float4 b1v = ((const float4*)P.b2)[sub * 2 + 1];
            float f[8];
            f[0] = fmaxf(fmaf(acc[0], di, b0.x), 0.f);
            f[1] = fmaxf(fmaf(acc[1], di, b0.y), 0.f);
            f[2] = fmaxf(fmaf(acc[2], di, b0.z), 0.f);
            f[3] = fmaxf(fmaf(acc[3], di, b0.w), 0.f);
            f[4] = fmaxf(fmaf(acc[4], di, b1v.x), 0.f);
            f[5] = fmaxf(fmaf(acc[5], di, b1v.y), 0.f);
            f[6] = fmaxf(fmaf(acc[6], di, b1v.z), 0.f);
            f[7] = fmaxf(fmaf(acc[7], di, b1v.w), 0.f);
            __syncthreads();   // previous iteration's classifier reads done
#pragma unroll
            for (int j = 0; j < 8; ++j) sm.sA[nl][sub * 8 + j] = f[j];
            __syncthreads();

            int col = tid & 15;
            float p0 = 0.f, p1 = 0.f;
#pragma unroll 4
            for (int k = 0; k < 128; k += 2) {
                p0 = fmaf(sm.sA[nl][k], P.Wc[k * 16 + col], p0);
                p1 = fmaf(sm.sA[nl][k + 1], P.Wc[(k + 1) * 16 + col], p1);
            }
            if (node < P.n) P.out[(size_t)node * 16 + col] = p0 + p1 + P.bc[col];
        }
    }
}

// ---------------- launch ----------------

extern "C" void kernel_launch(void* const* d_in, const int* in_sizes, int n_in,
                              void* d_out, int out_size, void* d_ws, size_t ws_size,
                              hipStream_t stream) {
    const int n = in_sizes[0] / 128;  // 50000
    const int E = in_sizes[1] / 2;    // 1,600,000
    const int nbuckets = (n + NPB - 1) / NPB;  // 196

    char* p = (char*)d_ws;
    auto alloc = [&](size_t bytes) {
        char* q = p;
        p += (bytes + 255) & ~(size_t)255;
        return q;
    };
    int*    bcursor  = (int*)alloc(256 * 4);
    int*    rowstart = (int*)alloc((size_t)n * 4);
    int*    rowend   = (int*)alloc((size_t)n * 4);
    float*  dinv     = (float*)alloc((size_t)n * 4);
    ushort* Wt1      = (ushort*)alloc(128 * 128 * 2);
    ushort* Wt2      = (ushort*)alloc(128 * 128 * 2);
    uint*   pay      = (uint*)alloc((size_t)nbuckets * CAP * 4);
    int*    colidx   = (int*)alloc((size_t)nbuckets * CAP * 4);
    uint*   bufA     = (uint*)alloc((size_t)n * 64 * 4);  // bf16 h'
    uint*   bufB     = (uint*)alloc((size_t)n * 64 * 4);  // bf16 a1
    if ((size_t)(p - (char*)d_ws) > ws_size) return;

    Params prm;
    prm.x  = (const float*)d_in[0];
    prm.src = (const int*)d_in[1];
    prm.dst = (const int*)d_in[1] + E;
    prm.W1 = (const float*)d_in[2];
    prm.b1 = (const float*)d_in[3];
    prm.W2 = (const float*)d_in[4];
    prm.b2 = (const float*)d_in[5];
    prm.Wc = (const float*)d_in[6];
    prm.bc = (const float*)d_in[7];
    prm.out = (float*)d_out;
    prm.bcursor = bcursor;
    prm.rowstart = rowstart;
    prm.rowend = rowend;
    prm.dinv = dinv;
    prm.Wt1 = Wt1;
    prm.Wt2 = Wt2;
    prm.pay = pay;
    prm.colidx = colidx;
    prm.bufA = bufA;
    prm.bufB = bufB;
    prm.n = n;
    prm.E = E;
    prm.nbuckets = nbuckets;
    prm.ntile64 = (n + 63) / 64;   // 782
    prm.ntile16 = (n + 15) / 16;   // 3125

    void* kargs[] = { &prm };
    hipLaunchCooperativeKernel((void*)gcn_all, dim3(GRID), dim3(256), kargs, 0, stream);
}

// Round 11
// 315.597 us; speedup vs baseline: 2.1407x; 2.1407x over previous
//
#include <hip/hip_runtime.h>
#include <hip/hip_bf16.h>

// GCN on MI355X — 5 launches (R10's cooperative mega-kernel regressed 2.4x:
// 2 blocks/CU co-residency cap starved the latency-bound aggregates of TLP):
//   K1 setup      : bcursor init + deg zero + W1,W2 -> bf16 W^T
//   K2 bin_edges  : bucket-binned edge scatter + deg[] histogram (L2-resident)
//   K3 build_gemm1: blocks<196 build_rows (CSR) ∥ rest gemm1 (di from deg)
//   K4 agg_gemm2  : a1 = relu(di*(self+Σh1')+b1) -> LDS; h2' = dinv⊙(a1@W2)
//                   (row-local fusion: 16 agg nodes == one MFMA A-tile)
//   K5 agg_out    : a2 = relu(di*(self+Σh2')+b2); out = a2@Wc + bc
// Aggregate: one NODE per 16-lane quarter, 8-edge unrolled unmasked loop +
// compensated masked tail; h pre-scaled by dinv (GCN norm identity).
// h bf16; accumulation fp32. Requires n <= 65536.

typedef unsigned int uint;
typedef unsigned short ushort;
typedef __attribute__((ext_vector_type(8))) short bf16x8;
typedef __attribute__((ext_vector_type(4))) float f32x4;

#define NPB 256
#define CAP 12288   // edges per bucket region; mean 8192, sd ~90

static __device__ __forceinline__ ushort f2bf(float f) {
    unsigned u = __float_as_uint(f);
    u += 0x7fffu + ((u >> 16) & 1u);   // round-to-nearest-even
    return (ushort)(u >> 16);
}
static __device__ __forceinline__ uint pack2(float a, float b) {
    return (uint)f2bf(a) | ((uint)f2bf(b) << 16);
}
static __device__ __forceinline__ float lo2f(uint u) { return __uint_as_float(u << 16); }
static __device__ __forceinline__ float hi2f(uint u) { return __uint_as_float(u & 0xffff0000u); }

#define UNPACK8(dst, u)                                        \
    dst[0] = lo2f(u.x); dst[1] = hi2f(u.x);                    \
    dst[2] = lo2f(u.y); dst[3] = hi2f(u.y);                    \
    dst[4] = lo2f(u.z); dst[5] = hi2f(u.z);                    \
    dst[6] = lo2f(u.w); dst[7] = hi2f(u.w);

// ---------------- K1: setup ----------------
__global__ __launch_bounds__(256) void setup(int* __restrict__ bcursor,
                                             int* __restrict__ deg,
                                             const float* __restrict__ W1,
                                             const float* __restrict__ W2,
                                             ushort* __restrict__ Wt1,
                                             ushort* __restrict__ Wt2,
                                             int n, int nbuckets) {
    int gid = blockIdx.x * 256 + threadIdx.x;     // grid 64*256 = 16384
    if (gid < nbuckets) bcursor[gid] = gid * CAP;
    for (int i = gid; i < n; i += 64 * 256) deg[i] = 0;
    {   // 128x128 transpose to [n][k] bf16
        int k = gid >> 7, nn = gid & 127;
        Wt1[nn * 128 + k] = f2bf(W1[gid]);
        Wt2[nn * 128 + k] = f2bf(W2[gid]);
    }
}

// ---------------- K2: bin_edges + deg histogram ----------------
__global__ __launch_bounds__(256) void bin_edges(const int* __restrict__ src,
                                                 const int* __restrict__ dst,
                                                 int* __restrict__ bcursor,
                                                 int* __restrict__ deg,
                                                 uint* __restrict__ pay,
                                                 int E, int nbuckets) {
    __shared__ int h[256];
    __shared__ int base[256];
    int tid = threadIdx.x;
    h[tid] = 0;
    __syncthreads();
    int chunk = (E + gridDim.x - 1) / gridDim.x;
    int i0 = blockIdx.x * chunk;
    int i1 = min(E, i0 + chunk);
    for (int i = i0 + tid; i < i1; i += 256) {
        int d = dst[i];
        atomicAdd(&h[d >> 8], 1);
        atomicAdd(&deg[d], 1);       // 200KB array: L2-resident atomics
    }
    __syncthreads();
    if (tid < nbuckets) base[tid] = h[tid] ? atomicAdd(&bcursor[tid], h[tid]) : 0;
    __syncthreads();
    h[tid] = 0;
    __syncthreads();
    for (int i = i0 + tid; i < i1; i += 256) {
        int d = dst[i];
        int b = d >> 8;
        int pos = base[b] + atomicAdd(&h[b], 1);
        pay[pos] = (uint)src[i] | ((uint)(d & 255) << 24);
    }
}

// ---------------- K3: build_rows ∥ gemm1 (dual-role) ----------------
// blocks [0,nbuckets): CSR finalize; blocks [nbuckets, nbuckets+ntile64): gemm1.
// gemm1 computes di = rsqrt(deg+1) itself (dinv[] is being written concurrently).
__global__ __launch_bounds__(256) void build_gemm1(const uint* __restrict__ pay,
                                                   const int* __restrict__ bcursor,
                                                   int* __restrict__ rowstart,
                                                   int* __restrict__ rowend,
                                                   float* __restrict__ dinv,
                                                   int* __restrict__ colidx,
                                                   const float* __restrict__ x,
                                                   const ushort* __restrict__ Wt1,
                                                   const int* __restrict__ deg,
                                                   uint* __restrict__ bufA,
                                                   int n, int nbuckets) {
    __shared__ int s_hist[256];
    __shared__ int s_sc[256];
    __shared__ int s_cur[256];
    __shared__ __align__(16) ushort sOut[4][16][136];
    int tid = threadIdx.x;

    if ((int)blockIdx.x < nbuckets) {
        // ---- build_rows ----
        int b = blockIdx.x;
        int node0 = b * NPB;
        int s = b * CAP, e = bcursor[b];
        s_hist[tid] = 0;
        __syncthreads();
        for (int i = s + tid; i < e; i += 256) atomicAdd(&s_hist[pay[i] >> 24], 1);
        __syncthreads();
        int v = s_hist[tid];
        s_sc[tid] = v;
        __syncthreads();
        for (int d = 1; d < 256; d <<= 1) {
            int xx = (tid >= d) ? s_sc[tid - d] : 0;
            __syncthreads();
            s_sc[tid] += xx;
            __syncthreads();
        }
        int excl = s_sc[tid] - v;
        s_cur[tid] = s + excl;
        int node = node0 + tid;
        if (node < n) {
            rowstart[node] = s + excl;
            rowend[node] = s + excl + v;
            dinv[node] = rsqrtf((float)(v + 1));  // +1 self-loop
        }
        __syncthreads();
        for (int i = s + tid; i < e; i += 256) {
            uint pp = pay[i];
            int pos = atomicAdd(&s_cur[pp >> 24], 1);
            colidx[pos] = (int)(pp & 0xffffffu);
        }
    } else {
        // ---- gemm1: h1' = rsqrt(deg+1) ⊙ (x@W1), bf16 out ----
        const int t = blockIdx.x - nbuckets;
        const int wave = tid >> 6;
        const int lane = tid & 63;
        const int quad = lane >> 4, l16 = lane & 15;
        const int m0 = t * 64 + wave * 16;

        f32x4 acc[8];
#pragma unroll
        for (int i = 0; i < 8; ++i) acc[i] = (f32x4){0.f, 0.f, 0.f, 0.f};

        int arow = m0 + l16;
        arow = arow < n ? arow : n - 1;

#pragma unroll
        for (int ks = 0; ks < 4; ++ks) {
            const float* px = &x[(size_t)arow * 128 + ks * 32 + quad * 8];
            float4 x0 = *(const float4*)px;
            float4 x1 = *(const float4*)(px + 4);
            ushort av[8] = {f2bf(x0.x), f2bf(x0.y), f2bf(x0.z), f2bf(x0.w),
                            f2bf(x1.x), f2bf(x1.y), f2bf(x1.z), f2bf(x1.w)};
            bf16x8 a = *(const bf16x8*)av;
#pragma unroll
            for (int nt = 0; nt < 8; ++nt) {
                bf16x8 b = *(const bf16x8*)&Wt1[(size_t)(nt * 16 + l16) * 128 + ks * 32 + quad * 8];
                acc[nt] = __builtin_amdgcn_mfma_f32_16x16x32_bf16(a, b, acc[nt], 0, 0, 0);
            }
        }

        float dv[4];
#pragma unroll
        for (int r = 0; r < 4; ++r) {
            int rr = m0 + quad * 4 + r;
            dv[r] = rsqrtf((float)(deg[rr < n ? rr : n - 1] + 1));
        }
#pragma unroll
        for (int nt = 0; nt < 8; ++nt)
#pragma unroll
            for (int r = 0; r < 4; ++r)
                sOut[wave][quad * 4 + r][nt * 16 + l16] = f2bf(acc[nt][r] * dv[r]);
        __syncthreads();

#pragma unroll
        for (int i = 0; i < 4; ++i) {
            int linear = i * 64 + lane;
            int row = linear >> 4, chunk = linear & 15;
            int rr = m0 + row;
            if (rr < n) {
                uint4 v = *(const uint4*)&sOut[wave][row][chunk * 8];
                *(uint4*)&bufA[(size_t)rr * 64 + chunk * 4] = v;
            }
        }
    }
}

// ---- aggregate gather: one node per 16-lane quarter, 8-edge unrolled ----
static __device__ __forceinline__ void gather_q(const uint4* __restrict__ H4,
                                                int s, int e, int nn, int sub,
                                                const int* __restrict__ colidx,
                                                float acc[8]) {
    uint4 su = H4[(size_t)nn * 16 + sub];
    float t[8];
    UNPACK8(t, su);
#pragma unroll
    for (int j = 0; j < 8; ++j) acc[j] = t[j];   // self term (pre-scaled h')

    int p = s;
    for (; p + 8 <= e; p += 8) {
        int c[8];
#pragma unroll
        for (int i = 0; i < 8; ++i) c[i] = colidx[p + i];
        uint4 u[8];
#pragma unroll
        for (int i = 0; i < 8; ++i) u[i] = H4[(size_t)c[i] * 16 + sub];
#pragma unroll
        for (int i = 0; i < 8; ++i) {
            float a[8];
            UNPACK8(a, u[i]);
#pragma unroll
            for (int j = 0; j < 8; ++j) acc[j] += a[j];
        }
    }
    if (p < e) {
        int c[8];
#pragma unroll
        for (int i = 0; i < 8; ++i) c[i] = (p + i < e) ? colidx[p + i] : nn;
        uint4 u[8];
#pragma unroll
        for (int i = 0; i < 8; ++i) u[i] = H4[(size_t)c[i] * 16 + sub];
#pragma unroll
        for (int i = 0; i < 8; ++i) {
            float a[8];
            UNPACK8(a, u[i]);
#pragma unroll
            for (int j = 0; j < 8; ++j) acc[j] += a[j];
        }
        float pad = (float)(p + 8 - e);
#pragma unroll
        for (int j = 0; j < 8; ++j) acc[j] -= pad * t[j];
    }
}

// ---------------- K4: agg_mid fused with gemm2 ----------------
// 16 nodes/block. Phase A: gather a1 rows into LDS (bf16). Phase B: the 16
// rows are one MFMA A-tile; wave w computes output cols [w*32, w*32+32).
__global__ __launch_bounds__(256) void agg_gemm2(const uint4* __restrict__ H4,
                                                 const int* __restrict__ rowstart,
                                                 const int* __restrict__ rowend,
                                                 const int* __restrict__ colidx,
                                                 const float* __restrict__ dinv,
                                                 const float* __restrict__ b1,
                                                 const ushort* __restrict__ Wt2,
                                                 uint* __restrict__ Yb, int n) {
    __shared__ __align__(16) ushort sA[16][136];  // a1 (MFMA A source)
    __shared__ __align__(16) ushort sO[16][136];  // h2' staging
    int tid = threadIdx.x;
    int sub = tid & 15;
    int nl = tid >> 4;
    int node0 = blockIdx.x * 16;
    int node = node0 + nl;
    int nn = node < n ? node : n - 1;
    int s = rowstart[nn], e = rowend[nn];
    float di = dinv[nn];

    float acc[8];
    gather_q(H4, s, e, nn, sub, colidx, acc);
    {
        float4 c0 = ((const float4*)b1)[sub * 2];
        float4 c1 = ((const float4*)b1)[sub * 2 + 1];
        float f0 = fmaxf(fmaf(acc[0], di, c0.x), 0.f);
        float f1 = fmaxf(fmaf(acc[1], di, c0.y), 0.f);
        float f2 = fmaxf(fmaf(acc[2], di, c0.z), 0.f);
        float f3 = fmaxf(fmaf(acc[3], di, c0.w), 0.f);
        float f4 = fmaxf(fmaf(acc[4], di, c1.x), 0.f);
        float f5 = fmaxf(fmaf(acc[5], di, c1.y), 0.f);
        float f6 = fmaxf(fmaf(acc[6], di, c1.z), 0.f);
        float f7 = fmaxf(fmaf(acc[7], di, c1.w), 0.f);
        uint4 v;
        v.x = pack2(f0, f1); v.y = pack2(f2, f3);
        v.z = pack2(f4, f5); v.w = pack2(f6, f7);
        *(uint4*)&sA[nl][sub * 8] = v;
    }
    __syncthreads();

    // Phase B: h2' = dinv ⊙ (a1 @ W2) for this block's 16 rows
    const int wave = tid >> 6;
    const int lane = tid & 63;
    const int quad = lane >> 4, l16 = lane & 15;
    f32x4 acc2[2];
    acc2[0] = (f32x4){0.f, 0.f, 0.f, 0.f};
    acc2[1] = (f32x4){0.f, 0.f, 0.f, 0.f};
#pragma unroll
    for (int ks = 0; ks < 4; ++ks) {
        bf16x8 a = *(const bf16x8*)&sA[l16][ks * 32 + quad * 8];
#pragma unroll
        for (int t = 0; t < 2; ++t) {
            int nt = wave * 2 + t;
            bf16x8 b = *(const bf16x8*)&Wt2[(size_t)(nt * 16 + l16) * 128 + ks * 32 + quad * 8];
            acc2[t] = __builtin_amdgcn_mfma_f32_16x16x32_bf16(a, b, acc2[t], 0, 0, 0);
        }
    }
#pragma unroll
    for (int r = 0; r < 4; ++r) {
        int rr = node0 + quad * 4 + r;
        float dv = dinv[rr < n ? rr : n - 1];
#pragma unroll
        for (int t = 0; t < 2; ++t)
            sO[quad * 4 + r][(wave * 2 + t) * 16 + l16] = f2bf(acc2[t][r] * dv);
    }
    __syncthreads();

    {
        int row = tid >> 4, chunk = tid & 15;
        int rr = node0 + row;
        if (rr < n) {
            uint4 v = *(const uint4*)&sO[row][chunk * 8];
            *(uint4*)&Yb[(size_t)rr * 64 + chunk * 4] = v;
        }
    }
}

// ---------------- K5: agg_out + classifier ----------------
__global__ __launch_bounds__(256) void agg_out_q(const uint4* __restrict__ H4,
                                                 const int* __restrict__ rowstart,
                                                 const int* __restrict__ rowend,
                                                 const int* __restrict__ colidx,
                                                 const float* __restrict__ dinv,
                                                 const float* __restrict__ bias,
                                                 const float* __restrict__ Wc,
                                                 const float* __restrict__ bc,
                                                 float* __restrict__ out, int n) {
    __shared__ float sA[16][129];
    int tid = threadIdx.x;
    int sub = tid & 15;
    int nl = tid >> 4;
    int node = blockIdx.x * 16 + nl;
    int nn = node < n ? node : n - 1;
    int s = rowstart[nn], e = rowend[nn];
    float di = dinv[nn];

    float acc[8];
    gather_q(H4, s, e, nn, sub, colidx, acc);

    {
        float4 b0 = ((const float4*)bias)[sub * 2];
        float4 b1v = ((const float4*)bias)[sub * 2 + 1];
        float f[8];
        f[0] = fmaxf(fmaf(acc[0], di, b0.x), 0.f);
        f[1] = fmaxf(fmaf(acc[1], di, b0.y), 0.f);
        f[2] = fmaxf(fmaf(acc[2], di, b0.z), 0.f);
        f[3] = fmaxf(fmaf(acc[3], di, b0.w), 0.f);
        f[4] = fmaxf(fmaf(acc[4], di, b1v.x), 0.f);
        f[5] = fmaxf(fmaf(acc[5], di, b1v.y), 0.f);
        f[6] = fmaxf(fmaf(acc[6], di, b1v.z), 0.f);
        f[7] = fmaxf(fmaf(acc[7], di, b1v.w), 0.f);
#pragma unroll
        for (int j = 0; j < 8; ++j) sA[nl][sub * 8 + j] = f[j];
    }
    __syncthreads();

    int col = tid & 15;
    float p0 = 0.f, p1 = 0.f;
#pragma unroll 4
    for (int k = 0; k < 128; k += 2) {
        p0 = fmaf(sA[nl][k], Wc[k * 16 + col], p0);
        p1 = fmaf(sA[nl][k + 1], Wc[(k + 1) * 16 + col], p1);
    }
    if (node < n) out[(size_t)node * 16 + col] = p0 + p1 + bc[col];
}

// ---------------- launch ----------------

extern "C" void kernel_launch(void* const* d_in, const int* in_sizes, int n_in,
                              void* d_out, int out_size, void* d_ws, size_t ws_size,
                              hipStream_t stream) {
    const float* x  = (const float*)d_in[0];
    const int*   ei = (const int*)d_in[1];
    const float* W1 = (const float*)d_in[2];
    const float* b1 = (const float*)d_in[3];
    const float* W2 = (const float*)d_in[4];
    const float* b2 = (const float*)d_in[5];
    const float* Wc = (const float*)d_in[6];
    const float* bc = (const float*)d_in[7];
    float* out = (float*)d_out;

    const int n = in_sizes[0] / 128;  // 50000
    const int E = in_sizes[1] / 2;    // 1,600,000
    const int* src = ei;
    const int* dst = ei + E;
    const int nbuckets = (n + NPB - 1) / NPB;  // 196

    char* p = (char*)d_ws;
    auto alloc = [&](size_t bytes) {
        char* q = p;
        p += (bytes + 255) & ~(size_t)255;
        return q;
    };
    int*    bcursor  = (int*)alloc(256 * 4);
    int*    deg      = (int*)alloc((size_t)n * 4);
    int*    rowstart = (int*)alloc((size_t)n * 4);
    int*    rowend   = (int*)alloc((size_t)n * 4);
    float*  dinv     = (float*)alloc((size_t)n * 4);
    ushort* Wt1      = (ushort*)alloc(128 * 128 * 2);
    ushort* Wt2      = (ushort*)alloc(128 * 128 * 2);
    uint*   pay      = (uint*)alloc((size_t)nbuckets * CAP * 4);
    int*    colidx   = (int*)alloc((size_t)nbuckets * CAP * 4);
    uint*   bufA     = (uint*)alloc((size_t)n * 64 * 4);  // bf16 h1'
    uint*   bufB     = (uint*)alloc((size_t)n * 64 * 4);  // bf16 h2'
    if ((size_t)(p - (char*)d_ws) > ws_size) return;

    const int ntile64 = (n + 63) / 64;   // 782
    const int aggb = (n + 15) / 16;      // 3125

    setup<<<64, 256, 0, stream>>>(bcursor, deg, W1, W2, Wt1, Wt2, n, nbuckets);
    bin_edges<<<256, 256, 0, stream>>>(src, dst, bcursor, deg, pay, E, nbuckets);
    build_gemm1<<<nbuckets + ntile64, 256, 0, stream>>>(pay, bcursor, rowstart, rowend,
                                                        dinv, colidx, x, Wt1, deg, bufA,
                                                        n, nbuckets);
    agg_gemm2<<<aggb, 256, 0, stream>>>((const uint4*)bufA, rowstart, rowend, colidx,
                                        dinv, b1, Wt2, bufB, n);
    agg_out_q<<<aggb, 256, 0, stream>>>((const uint4*)bufB, rowstart, rowend, colidx,
                                        dinv, b2, Wc, bc, out, n);
}

// Round 12
// 305.476 us; speedup vs baseline: 2.2116x; 1.0331x over previous
//
#include <hip/hip_runtime.h>
#include <hip/hip_bf16.h>

// GCN on MI355X — 5 launches:
//   K1 setup      : bcursor init + deg zero + W1,W2 -> bf16 W^T
//   K2 bin_edges  : bucket-binned edge scatter + deg[] histogram
//                   (512 blocks x 1024 thr — R11 ran 256x256 = 12.5% occ cap)
//   K3 build_gemm1: blocks<196 build CSR (512 thr) ∥ rest gemm1, 2 tiles/block
//   K4 agg_gemm2  : a1 = relu(di*(self+Σh1')+b1) -> LDS; h2' = dinv⊙(a1@W2)
//   K5 agg_out    : a2 = relu(di*(self+Σh2')+b2); out = a2@Wc + bc
// Aggregate: one NODE per 16-lane quarter, 8-edge unrolled unmasked loop +
// compensated masked tail; h pre-scaled by dinv (GCN norm identity).
// h bf16; accumulation fp32. Requires n <= 65536.

typedef unsigned int uint;
typedef unsigned short ushort;
typedef __attribute__((ext_vector_type(8))) short bf16x8;
typedef __attribute__((ext_vector_type(4))) float f32x4;

#define NPB 256
#define CAP 12288   // edges per bucket region; mean 8192, sd ~90

static __device__ __forceinline__ ushort f2bf(float f) {
    unsigned u = __float_as_uint(f);
    u += 0x7fffu + ((u >> 16) & 1u);   // round-to-nearest-even
    return (ushort)(u >> 16);
}
static __device__ __forceinline__ uint pack2(float a, float b) {
    return (uint)f2bf(a) | ((uint)f2bf(b) << 16);
}
static __device__ __forceinline__ float lo2f(uint u) { return __uint_as_float(u << 16); }
static __device__ __forceinline__ float hi2f(uint u) { return __uint_as_float(u & 0xffff0000u); }

#define UNPACK8(dst, u)                                        \
    dst[0] = lo2f(u.x); dst[1] = hi2f(u.x);                    \
    dst[2] = lo2f(u.y); dst[3] = hi2f(u.y);                    \
    dst[4] = lo2f(u.z); dst[5] = hi2f(u.z);                    \
    dst[6] = lo2f(u.w); dst[7] = hi2f(u.w);

// ---------------- K1: setup ----------------
__global__ __launch_bounds__(256) void setup(int* __restrict__ bcursor,
                                             int* __restrict__ deg,
                                             const float* __restrict__ W1,
                                             const float* __restrict__ W2,
                                             ushort* __restrict__ Wt1,
                                             ushort* __restrict__ Wt2,
                                             int n, int nbuckets) {
    int gid = blockIdx.x * 256 + threadIdx.x;     // grid 64*256 = 16384
    if (gid < nbuckets) bcursor[gid] = gid * CAP;
    for (int i = gid; i < n; i += 64 * 256) deg[i] = 0;
    {   // 128x128 transpose to [n][k] bf16
        int k = gid >> 7, nn = gid & 127;
        Wt1[nn * 128 + k] = f2bf(W1[gid]);
        Wt2[nn * 128 + k] = f2bf(W2[gid]);
    }
}

// ---------------- K2: bin_edges + deg histogram (1024 threads) ----------------
__global__ __launch_bounds__(1024) void bin_edges(const int* __restrict__ src,
                                                  const int* __restrict__ dst,
                                                  int* __restrict__ bcursor,
                                                  int* __restrict__ deg,
                                                  uint* __restrict__ pay,
                                                  int E, int nbuckets) {
    __shared__ int h[256];
    __shared__ int base[256];
    int tid = threadIdx.x;
    if (tid < 256) h[tid] = 0;
    __syncthreads();
    int chunk = (E + gridDim.x - 1) / gridDim.x;
    int i0 = blockIdx.x * chunk;
    int i1 = min(E, i0 + chunk);
    for (int i = i0 + tid; i < i1; i += 1024) {
        int d = dst[i];
        atomicAdd(&h[d >> 8], 1);
        atomicAdd(&deg[d], 1);       // 200KB array: L2-resident atomics
    }
    __syncthreads();
    if (tid < nbuckets) base[tid] = h[tid] ? atomicAdd(&bcursor[tid], h[tid]) : 0;
    __syncthreads();
    if (tid < 256) h[tid] = 0;
    __syncthreads();
    for (int i = i0 + tid; i < i1; i += 1024) {
        int d = dst[i];
        int b = d >> 8;
        int pos = base[b] + atomicAdd(&h[b], 1);
        pay[pos] = (uint)src[i] | ((uint)(d & 255) << 24);
    }
}

// ---------------- K3: build_rows ∥ gemm1 (dual-role, 512 threads) ----------------
// blocks [0,nbuckets): CSR finalize (512-thread strides).
// blocks [nbuckets, nbuckets+391): gemm1, TWO 64-row tiles per block (8 waves).
__global__ __launch_bounds__(512) void build_gemm1(const uint* __restrict__ pay,
                                                   const int* __restrict__ bcursor,
                                                   int* __restrict__ rowstart,
                                                   int* __restrict__ rowend,
                                                   float* __restrict__ dinv,
                                                   int* __restrict__ colidx,
                                                   const float* __restrict__ x,
                                                   const ushort* __restrict__ Wt1,
                                                   const int* __restrict__ deg,
                                                   uint* __restrict__ bufA,
                                                   int n, int nbuckets, int ntile) {
    __shared__ int s_hist[256];
    __shared__ int s_sc[256];
    __shared__ int s_cur[256];
    __shared__ __align__(16) ushort sOut[8][16][136];  // 34.8 KB
    int tid = threadIdx.x;

    if ((int)blockIdx.x < nbuckets) {
        // ---- build_rows ----
        int b = blockIdx.x;
        int node0 = b * NPB;
        int s = b * CAP, e = bcursor[b];
        if (tid < 256) s_hist[tid] = 0;
        __syncthreads();
        for (int i = s + tid; i < e; i += 512) atomicAdd(&s_hist[pay[i] >> 24], 1);
        __syncthreads();
        int v = (tid < 256) ? s_hist[tid] : 0;
        if (tid < 256) s_sc[tid] = v;
        __syncthreads();
        for (int d = 1; d < 256; d <<= 1) {
            int xx = (tid < 256 && tid >= d) ? s_sc[tid - d] : 0;
            __syncthreads();
            if (tid < 256) s_sc[tid] += xx;
            __syncthreads();
        }
        if (tid < 256) {
            int excl = s_sc[tid] - v;
            s_cur[tid] = s + excl;
            int node = node0 + tid;
            if (node < n) {
                rowstart[node] = s + excl;
                rowend[node] = s + excl + v;
                dinv[node] = rsqrtf((float)(v + 1));  // +1 self-loop
            }
        }
        __syncthreads();
        for (int i = s + tid; i < e; i += 512) {
            uint pp = pay[i];
            int pos = atomicAdd(&s_cur[pp >> 24], 1);
            colidx[pos] = (int)(pp & 0xffffffu);
        }
    } else {
        // ---- gemm1: h1' = rsqrt(deg+1) ⊙ (x@W1), bf16 out; 2 tiles/block ----
        const int wave = tid >> 6;          // 0..7
        const int lane = tid & 63;
        const int quad = lane >> 4, l16 = lane & 15;
        const int tile = ((int)blockIdx.x - nbuckets) * 2 + (wave >> 2);
        const int m0 = tile * 64 + (wave & 3) * 16;
        bool active = tile < ntile;

        if (active) {
            f32x4 acc[8];
#pragma unroll
            for (int i = 0; i < 8; ++i) acc[i] = (f32x4){0.f, 0.f, 0.f, 0.f};

            int arow = m0 + l16;
            arow = arow < n ? arow : n - 1;

#pragma unroll
            for (int ks = 0; ks < 4; ++ks) {
                const float* px = &x[(size_t)arow * 128 + ks * 32 + quad * 8];
                float4 x0 = *(const float4*)px;
                float4 x1 = *(const float4*)(px + 4);
                ushort av[8] = {f2bf(x0.x), f2bf(x0.y), f2bf(x0.z), f2bf(x0.w),
                                f2bf(x1.x), f2bf(x1.y), f2bf(x1.z), f2bf(x1.w)};
                bf16x8 a = *(const bf16x8*)av;
#pragma unroll
                for (int nt = 0; nt < 8; ++nt) {
                    bf16x8 b = *(const bf16x8*)&Wt1[(size_t)(nt * 16 + l16) * 128 + ks * 32 + quad * 8];
                    acc[nt] = __builtin_amdgcn_mfma_f32_16x16x32_bf16(a, b, acc[nt], 0, 0, 0);
                }
            }

            float dv[4];
#pragma unroll
            for (int r = 0; r < 4; ++r) {
                int rr = m0 + quad * 4 + r;
                dv[r] = rsqrtf((float)(deg[rr < n ? rr : n - 1] + 1));
            }
#pragma unroll
            for (int nt = 0; nt < 8; ++nt)
#pragma unroll
                for (int r = 0; r < 4; ++r)
                    sOut[wave][quad * 4 + r][nt * 16 + l16] = f2bf(acc[nt][r] * dv[r]);
        }
        __syncthreads();

        if (active) {
#pragma unroll
            for (int i = 0; i < 4; ++i) {
                int linear = i * 64 + lane;
                int row = linear >> 4, chunk = linear & 15;
                int rr = m0 + row;
                if (rr < n) {
                    uint4 v = *(const uint4*)&sOut[wave][row][chunk * 8];
                    *(uint4*)&bufA[(size_t)rr * 64 + chunk * 4] = v;
                }
            }
        }
    }
}

// ---- aggregate gather: one node per 16-lane quarter, 8-edge unrolled ----
static __device__ __forceinline__ void gather_q(const uint4* __restrict__ H4,
                                                int s, int e, int nn, int sub,
                                                const int* __restrict__ colidx,
                                                float acc[8]) {
    uint4 su = H4[(size_t)nn * 16 + sub];
    float t[8];
    UNPACK8(t, su);
#pragma unroll
    for (int j = 0; j < 8; ++j) acc[j] = t[j];   // self term (pre-scaled h')

    int p = s;
    for (; p + 8 <= e; p += 8) {
        int c[8];
#pragma unroll
        for (int i = 0; i < 8; ++i) c[i] = colidx[p + i];
        uint4 u[8];
#pragma unroll
        for (int i = 0; i < 8; ++i) u[i] = H4[(size_t)c[i] * 16 + sub];
#pragma unroll
        for (int i = 0; i < 8; ++i) {
            float a[8];
            UNPACK8(a, u[i]);
#pragma unroll
            for (int j = 0; j < 8; ++j) acc[j] += a[j];
        }
    }
    if (p < e) {
        int c[8];
#pragma unroll
        for (int i = 0; i < 8; ++i) c[i] = (p + i < e) ? colidx[p + i] : nn;
        uint4 u[8];
#pragma unroll
        for (int i = 0; i < 8; ++i) u[i] = H4[(size_t)c[i] * 16 + sub];
#pragma unroll
        for (int i = 0; i < 8; ++i) {
            float a[8];
            UNPACK8(a, u[i]);
#pragma unroll
            for (int j = 0; j < 8; ++j) acc[j] += a[j];
        }
        float pad = (float)(p + 8 - e);
#pragma unroll
        for (int j = 0; j < 8; ++j) acc[j] -= pad * t[j];
    }
}

// ---------------- K4: agg_mid fused with gemm2 ----------------
__global__ __launch_bounds__(256) void agg_gemm2(const uint4* __restrict__ H4,
                                                 const int* __restrict__ rowstart,
                                                 const int* __restrict__ rowend,
                                                 const int* __restrict__ colidx,
                                                 const float* __restrict__ dinv,
                                                 const float* __restrict__ b1,
                                                 const ushort* __restrict__ Wt2,
                                                 uint* __restrict__ Yb, int n) {
    __shared__ __align__(16) ushort sA[16][136];  // a1 (MFMA A source)
    __shared__ __align__(16) ushort sO[16][136];  // h2' staging
    int tid = threadIdx.x;
    int sub = tid & 15;
    int nl = tid >> 4;
    int node0 = blockIdx.x * 16;
    int node = node0 + nl;
    int nn = node < n ? node : n - 1;
    int s = rowstart[nn], e = rowend[nn];
    float di = dinv[nn];

    float acc[8];
    gather_q(H4, s, e, nn, sub, colidx, acc);
    {
        float4 c0 = ((const float4*)b1)[sub * 2];
        float4 c1 = ((const float4*)b1)[sub * 2 + 1];
        float f0 = fmaxf(fmaf(acc[0], di, c0.x), 0.f);
        float f1 = fmaxf(fmaf(acc[1], di, c0.y), 0.f);
        float f2 = fmaxf(fmaf(acc[2], di, c0.z), 0.f);
        float f3 = fmaxf(fmaf(acc[3], di, c0.w), 0.f);
        float f4 = fmaxf(fmaf(acc[4], di, c1.x), 0.f);
        float f5 = fmaxf(fmaf(acc[5], di, c1.y), 0.f);
        float f6 = fmaxf(fmaf(acc[6], di, c1.z), 0.f);
        float f7 = fmaxf(fmaf(acc[7], di, c1.w), 0.f);
        uint4 v;
        v.x = pack2(f0, f1); v.y = pack2(f2, f3);
        v.z = pack2(f4, f5); v.w = pack2(f6, f7);
        *(uint4*)&sA[nl][sub * 8] = v;
    }
    __syncthreads();

    // Phase B: h2' = dinv ⊙ (a1 @ W2) for this block's 16 rows
    const int wave = tid >> 6;
    const int lane = tid & 63;
    const int quad = lane >> 4, l16 = lane & 15;
    f32x4 acc2[2];
    acc2[0] = (f32x4){0.f, 0.f, 0.f, 0.f};
    acc2[1] = (f32x4){0.f, 0.f, 0.f, 0.f};
#pragma unroll
    for (int ks = 0; ks < 4; ++ks) {
        bf16x8 a = *(const bf16x8*)&sA[l16][ks * 32 + quad * 8];
#pragma unroll
        for (int t = 0; t < 2; ++t) {
            int nt = wave * 2 + t;
            bf16x8 b = *(const bf16x8*)&Wt2[(size_t)(nt * 16 + l16) * 128 + ks * 32 + quad * 8];
            acc2[t] = __builtin_amdgcn_mfma_f32_16x16x32_bf16(a, b, acc2[t], 0, 0, 0);
        }
    }
#pragma unroll
    for (int r = 0; r < 4; ++r) {
        int rr = node0 + quad * 4 + r;
        float dv = dinv[rr < n ? rr : n - 1];
#pragma unroll
        for (int t = 0; t < 2; ++t)
            sO[quad * 4 + r][(wave * 2 + t) * 16 + l16] = f2bf(acc2[t][r] * dv);
    }
    __syncthreads();

    {
        int row = tid >> 4, chunk = tid & 15;
        int rr = node0 + row;
        if (rr < n) {
            uint4 v = *(const uint4*)&sO[row][chunk * 8];
            *(uint4*)&Yb[(size_t)rr * 64 + chunk * 4] = v;
        }
    }
}

// ---------------- K5: agg_out + classifier ----------------
__global__ __launch_bounds__(256) void agg_out_q(const uint4* __restrict__ H4,
                                                 const int* __restrict__ rowstart,
                                                 const int* __restrict__ rowend,
                                                 const int* __restrict__ colidx,
                                                 const float* __restrict__ dinv,
                                                 const float* __restrict__ bias,
                                                 const float* __restrict__ Wc,
                                                 const float* __restrict__ bc,
                                                 float* __restrict__ out, int n) {
    __shared__ float sA[16][129];
    int tid = threadIdx.x;
    int sub = tid & 15;
    int nl = tid >> 4;
    int node = blockIdx.x * 16 + nl;
    int nn = node < n ? node : n - 1;
    int s = rowstart[nn], e = rowend[nn];
    float di = dinv[nn];

    float acc[8];
    gather_q(H4, s, e, nn, sub, colidx, acc);

    {
        float4 b0 = ((const float4*)bias)[sub * 2];
        float4 b1v = ((const float4*)bias)[sub * 2 + 1];
        float f[8];
        f[0] = fmaxf(fmaf(acc[0], di, b0.x), 0.f);
        f[1] = fmaxf(fmaf(acc[1], di, b0.y), 0.f);
        f[2] = fmaxf(fmaf(acc[2], di, b0.z), 0.f);
        f[3] = fmaxf(fmaf(acc[3], di, b0.w), 0.f);
        f[4] = fmaxf(fmaf(acc[4], di, b1v.x), 0.f);
        f[5] = fmaxf(fmaf(acc[5], di, b1v.y), 0.f);
        f[6] = fmaxf(fmaf(acc[6], di, b1v.z), 0.f);
        f[7] = fmaxf(fmaf(acc[7], di, b1v.w), 0.f);
#pragma unroll
        for (int j = 0; j < 8; ++j) sA[nl][sub * 8 + j] = f[j];
    }
    __syncthreads();

    int col = tid & 15;
    float p0 = 0.f, p1 = 0.f;
#pragma unroll 4
    for (int k = 0; k < 128; k += 2) {
        p0 = fmaf(sA[nl][k], Wc[k * 16 + col], p0);
        p1 = fmaf(sA[nl][k + 1], Wc[(k + 1) * 16 + col], p1);
    }
    if (node < n) out[(size_t)node * 16 + col] = p0 + p1 + bc[col];
}

// ---------------- launch ----------------

extern "C" void kernel_launch(void* const* d_in, const int* in_sizes, int n_in,
                              void* d_out, int out_size, void* d_ws, size_t ws_size,
                              hipStream_t stream) {
    const float* x  = (const float*)d_in[0];
    const int*   ei = (const int*)d_in[1];
    const float* W1 = (const float*)d_in[2];
    const float* b1 = (const float*)d_in[3];
    const float* W2 = (const float*)d_in[4];
    const float* b2 = (const float*)d_in[5];
    const float* Wc = (const float*)d_in[6];
    const float* bc = (const float*)d_in[7];
    float* out = (float*)d_out;

    const int n = in_sizes[0] / 128;  // 50000
    const int E = in_sizes[1] / 2;    // 1,600,000
    const int* src = ei;
    const int* dst = ei + E;
    const int nbuckets = (n + NPB - 1) / NPB;  // 196

    char* p = (char*)d_ws;
    auto alloc = [&](size_t bytes) {
        char* q = p;
        p += (bytes + 255) & ~(size_t)255;
        return q;
    };
    int*    bcursor  = (int*)alloc(256 * 4);
    int*    deg      = (int*)alloc((size_t)n * 4);
    int*    rowstart = (int*)alloc((size_t)n * 4);
    int*    rowend   = (int*)alloc((size_t)n * 4);
    float*  dinv     = (float*)alloc((size_t)n * 4);
    ushort* Wt1      = (ushort*)alloc(128 * 128 * 2);
    ushort* Wt2      = (ushort*)alloc(128 * 128 * 2);
    uint*   pay      = (uint*)alloc((size_t)nbuckets * CAP * 4);
    int*    colidx   = (int*)alloc((size_t)nbuckets * CAP * 4);
    uint*   bufA     = (uint*)alloc((size_t)n * 64 * 4);  // bf16 h1'
    uint*   bufB     = (uint*)alloc((size_t)n * 64 * 4);  // bf16 h2'
    if ((size_t)(p - (char*)d_ws) > ws_size) return;

    const int ntile = (n + 63) / 64;           // 782 tiles
    const int gblocks = (ntile + 1) / 2;       // 391 gemm blocks (2 tiles each)
    const int aggb = (n + 15) / 16;            // 3125

    setup<<<64, 256, 0, stream>>>(bcursor, deg, W1, W2, Wt1, Wt2, n, nbuckets);
    bin_edges<<<512, 1024, 0, stream>>>(src, dst, bcursor, deg, pay, E, nbuckets);
    build_gemm1<<<nbuckets + gblocks, 512, 0, stream>>>(pay, bcursor, rowstart, rowend,
                                                        dinv, colidx, x, Wt1, deg, bufA,
                                                        n, nbuckets, ntile);
    agg_gemm2<<<aggb, 256, 0, stream>>>((const uint4*)bufA, rowstart, rowend, colidx,
                                        dinv, b1, Wt2, bufB, n);
    agg_out_q<<<aggb, 256, 0, stream>>>((const uint4*)bufB, rowstart, rowend, colidx,
                                        dinv, b2, Wc, bc, out, n);
}